// Round 1
// 226.679 us; speedup vs baseline: 1.0256x; 1.0256x over previous
//
#include <hip/hip_runtime.h>

#define B_ 8
#define T_ 4096
#define D_ 768
#define NH_ 12
#define M_ 64
#define ALPHA_ 0.1f

#define CCH 16         // chunks over T
#define CHUNK_T 256    // t per block

using half8 = __attribute__((ext_vector_type(8))) _Float16;
using short8 = __attribute__((ext_vector_type(8))) short;
using f32x4 = __attribute__((ext_vector_type(4))) float;

__device__ __forceinline__ unsigned int f2h2(float a, float b) {
    unsigned short ua = __builtin_bit_cast(unsigned short, (_Float16)a);
    unsigned short ub = __builtin_bit_cast(unsigned short, (_Float16)b);
    return (unsigned int)ua | ((unsigned int)ub << 16);
}
__device__ __forceinline__ float h2f(unsigned short u) {
    return (float)__builtin_bit_cast(_Float16, u);
}
// async global->LDS, 16 B per lane; LDS dst must be wave-uniform base + lane*16
__device__ __forceinline__ void gload_lds16(const void* g, void* l) {
    __builtin_amdgcn_global_load_lds(
        (const __attribute__((address_space(1))) unsigned int*)g,
        (__attribute__((address_space(3))) unsigned int*)l, 16, 0, 0);
}

// ---------------------------------------------------------------------------
// Kernel H16: H fp32 -> fp16, elementwise (25.2M elems). grid 6144 x 256.
// ---------------------------------------------------------------------------
__global__ __launch_bounds__(256) void kH16(const float* __restrict__ H,
                                            unsigned short* __restrict__ H16) {
    const int i = blockIdx.x * 256 + threadIdx.x;
#pragma unroll
    for (int j = 0; j < 4; ++j) {
        const int idx = i + j * 1572864;
        const float4 v = reinterpret_cast<const float4*>(H)[idx];
        uint2 pk = {f2h2(v.x, v.y), f2h2(v.z, v.w)};
        reinterpret_cast<uint2*>(H16)[idx] = pk;
    }
}

// ---------------------------------------------------------------------------
// Kernel 0: P[h,m,e] = (1/8) * sum_i proto[m, h*64+i] * W[h*64+i, e] -> fp16.
// ---------------------------------------------------------------------------
__global__ __launch_bounds__(256) void kP(const float* __restrict__ proto,
                                          const float* __restrict__ W,
                                          unsigned short* __restrict__ P16) {
    const int et = blockIdx.x;
    const int h  = blockIdx.y;
    const int tid = threadIdx.x;

    __shared__ __align__(16) float Ws[64 * 128];
    __shared__ __align__(16) float Ks[64 * 64];

#pragma unroll
    for (int j = 0; j < 8; ++j) {
        int f = tid + j * 256;
        int i = f >> 5, c4 = f & 31;
        const float4 v = *reinterpret_cast<const float4*>(
            W + (size_t)(h * 64 + i) * D_ + et * 128 + c4 * 4);
        *reinterpret_cast<float4*>(&Ws[i * 128 + c4 * 4]) = v;
    }
#pragma unroll
    for (int j = 0; j < 4; ++j) {
        int f = tid + j * 256;
        int m = f >> 4, i4 = f & 15;
        const float4 v = *reinterpret_cast<const float4*>(
            proto + (size_t)m * D_ + h * 64 + i4 * 4);
        Ks[(i4 * 4 + 0) * 64 + m] = v.x;
        Ks[(i4 * 4 + 1) * 64 + m] = v.y;
        Ks[(i4 * 4 + 2) * 64 + m] = v.z;
        Ks[(i4 * 4 + 3) * 64 + m] = v.w;
    }
    __syncthreads();

    const int m0 = (tid >> 5) * 8;
    const int e0 = (tid & 31) * 4;
    float acc[8][4];
#pragma unroll
    for (int i = 0; i < 8; ++i)
#pragma unroll
        for (int j = 0; j < 4; ++j) acc[i][j] = 0.f;

    for (int i = 0; i < 64; ++i) {
        const float4 bb = *reinterpret_cast<const float4*>(&Ws[i * 128 + e0]);
        const float4 a0 = *reinterpret_cast<const float4*>(&Ks[i * 64 + m0]);
        const float4 a1 = *reinterpret_cast<const float4*>(&Ks[i * 64 + m0 + 4]);
        const float a[8] = {a0.x, a0.y, a0.z, a0.w, a1.x, a1.y, a1.z, a1.w};
#pragma unroll
        for (int mi = 0; mi < 8; ++mi) {
            acc[mi][0] = fmaf(a[mi], bb.x, acc[mi][0]);
            acc[mi][1] = fmaf(a[mi], bb.y, acc[mi][1]);
            acc[mi][2] = fmaf(a[mi], bb.z, acc[mi][2]);
            acc[mi][3] = fmaf(a[mi], bb.w, acc[mi][3]);
        }
    }
#pragma unroll
    for (int mi = 0; mi < 8; ++mi) {
        size_t idx = (size_t)(h * 64 + m0 + mi) * D_ + et * 128 + e0;
        uint2 pk = {f2h2(acc[mi][0] * 0.125f, acc[mi][1] * 0.125f),
                    f2h2(acc[mi][2] * 0.125f, acc[mi][3] * 0.125f)};
        *reinterpret_cast<uint2*>(P16 + idx) = pk;
    }
}

// ---------------------------------------------------------------------------
// Kernel 1: per (chunk=256t, head-PAIR, batch). 512 threads / 8 waves; wave w
// owns (head_local = w>>2, t-quarter = w&3). A-tile (H16, full D) is staged
// ONCE per head pair (-40% staging traffic vs 1 head/block). Score GEMM via
// global_load_lds w=16 with granule XOR-swizzle; softmax in registers (no
// max-sub: scores ~N(0,1)); per-head sequential: pack wT -> 8-segment
// suffix scan -> fp16 MFMA partial.
// grid 768 (b = p&7 pins batch per XCD), dyn LDS 69632 B, 2 blocks/CU.
//
// LDS (bytes): [0,32768) A f16[256t][64k] swz | [32768,49152) B f16[2h][64m][64k]
//   alias: [0,33792) wT f16[64m][264t] | [33792,67584) Hh f16[64d][264t]
//   [67584,69632) segprod f32[8][64]
// ---------------------------------------------------------------------------
#define LDS_BYTES 69632

__global__ __launch_bounds__(512, 4) void k1(const unsigned short* __restrict__ H16,
                                             const unsigned short* __restrict__ P16,
                                             float* __restrict__ chunkprod,
                                             float* __restrict__ partial) {
    const int p = blockIdx.x;
    const int b = p & 7;
    const int s = p >> 3;
    const int hp = s % 6;          // head pair index
    const int c  = s / 6;
    const int tid = threadIdx.x;
    const int wv  = tid >> 6;      // 0..7
    const int lane = tid & 63;
    const int l15 = lane & 15;
    const int q4  = lane >> 4;
    const int hl  = wv >> 2;       // wave's head_local (0/1)
    const int tq  = wv & 3;        // wave's t-quarter

    extern __shared__ __align__(16) unsigned char smem[];
    unsigned short* wT = (unsigned short*)(smem);
    unsigned short* Hh = (unsigned short*)(smem + 33792);
    float* segprod = (float*)(smem + 67584);

    const size_t Hrow = (size_t)(b * T_ + c * CHUNK_T);
    const unsigned short* gA = H16 + Hrow * D_;
    const unsigned short* gB = P16 + (size_t)(hp * 2) * 64 * D_;

    // ======== score GEMM: 256t x (2h x 64m), K=768, fp16, DMA-staged ========
    f32x4 acc[4][4] = {};   // t = tq*64+tt*16+q4*4+rg (row), m = mt*16+l15 (col)

    for (int kt = 0; kt < 12; ++kt) {
        __syncthreads();
        // A: 2048 granules of 16 B; slot sl -> row r=sl>>3, lds-granule gp=sl&7,
        // fetched data granule g = gp ^ (r&7)
#pragma unroll
        for (int j = 0; j < 4; ++j) {
            int sl = j * 512 + tid;
            int r = sl >> 3, gp = sl & 7, g = gp ^ (r & 7);
            gload_lds16(gA + (size_t)r * D_ + kt * 64 + g * 8, smem + sl * 16);
        }
        // B: 1024 granules (2 heads x 512)
#pragma unroll
        for (int j = 0; j < 2; ++j) {
            int sl = j * 512 + tid;
            int r = (sl & 511) >> 3, gp = sl & 7, g = gp ^ (r & 7);
            gload_lds16(gB + (size_t)(j * 64 + r) * D_ + kt * 64 + g * 8,
                        smem + 32768 + sl * 16);
        }
        __syncthreads();
#pragma unroll
        for (int ks = 0; ks < 2; ++ks) {
            const int gp = ((ks * 4 + q4) ^ (l15 & 7)) * 16;
            half8 af[4], bf[4];
#pragma unroll
            for (int tt = 0; tt < 4; ++tt)
                af[tt] = *reinterpret_cast<const half8*>(
                    smem + (tq * 64 + tt * 16 + l15) * 128 + gp);
#pragma unroll
            for (int mt = 0; mt < 4; ++mt)
                bf[mt] = *reinterpret_cast<const half8*>(
                    smem + 32768 + hl * 8192 + (mt * 16 + l15) * 128 + gp);
#pragma unroll
            for (int tt = 0; tt < 4; ++tt)
#pragma unroll
                for (int mt = 0; mt < 4; ++mt)
                    acc[tt][mt] = __builtin_amdgcn_mfma_f32_16x16x32_f16(
                        af[tt], bf[mt], acc[tt][mt], 0, 0, 0);
        }
    }

    // ======== softmax over m in registers (reduce over l15), no max-sub ====
#pragma unroll
    for (int tt = 0; tt < 4; ++tt)
#pragma unroll
        for (int rg = 0; rg < 4; ++rg) {
            float e0 = __expf(acc[tt][0][rg]);
            float e1 = __expf(acc[tt][1][rg]);
            float e2 = __expf(acc[tt][2][rg]);
            float e3 = __expf(acc[tt][3][rg]);
            float sm = (e0 + e1) + (e2 + e3);
#pragma unroll
            for (int msk = 1; msk <= 8; msk <<= 1)
                sm += __shfl_xor(sm, msk, 64);
            float inv = __builtin_amdgcn_rcpf(sm);
            acc[tt][0][rg] = e0 * inv;
            acc[tt][1][rg] = e1 * inv;
            acc[tt][2][rg] = e2 * inv;
            acc[tt][3][rg] = e3 * inv;
        }
    __syncthreads();   // score-phase frag reads done; wT/Hh alias A/B

    const int m_s = tid & 63;
    const int g8  = tid >> 6;    // segment index (== wv)

    // ======== per-head: pack wT -> suffix scan -> partial GEMM =============
    for (int head = 0; head < 2; ++head) {
        const int h = hp * 2 + head;
        const int chunkIdx = (b * NH_ + h) * CCH + c;
        if (head) __syncthreads();   // prev head's partial frag reads done

        // pack w -> wT[m][t] fp16, pitch 264 (waves of this head only)
        if (hl == head) {
#pragma unroll
            for (int tt = 0; tt < 4; ++tt)
#pragma unroll
                for (int mt = 0; mt < 4; ++mt) {
                    uint2 pk = {f2h2(acc[tt][mt][0], acc[tt][mt][1]),
                                f2h2(acc[tt][mt][2], acc[tt][mt][3])};
                    *reinterpret_cast<uint2*>(
                        wT + (mt * 16 + l15) * 264 + tq * 64 + tt * 16 + q4 * 4) = pk;
                }
        }
        // stage Hh: H16[256t][64d] head slice -> [d][t], pitch 264 (all threads)
        {
            const int dp = tid & 31, tg = tid >> 5;
            const unsigned short* src = H16 + (Hrow + tg * 16) * D_ + h * 64 + 2 * dp;
            unsigned short* dst0 = Hh + (2 * dp) * 264 + tg * 16;
            unsigned short* dst1 = Hh + (2 * dp + 1) * 264 + tg * 16;
#pragma unroll
            for (int i = 0; i < 8; ++i) {
                unsigned int a = *reinterpret_cast<const unsigned int*>(
                    src + (size_t)(2 * i) * D_);
                unsigned int bb = *reinterpret_cast<const unsigned int*>(
                    src + (size_t)(2 * i + 1) * D_);
                *reinterpret_cast<unsigned int*>(dst0 + 2 * i) =
                    (a & 0xffffu) | (bb << 16);
                *reinterpret_cast<unsigned int*>(dst1 + 2 * i) =
                    (a >> 16) | (bb & 0xffff0000u);
            }
        }
        __syncthreads();

        // segmented suffix gate scan: 8 segments x 32 t, all 512 threads
        {
            unsigned short* rowp = wT + m_s * 264 + g8 * 32;
            float pband = 1.0f;
#pragma unroll
            for (int oct = 0; oct < 4; ++oct) {
                short8 v = *reinterpret_cast<const short8*>(rowp + oct * 8);
#pragma unroll
                for (int j = 0; j < 8; ++j)
                    pband *= fmaf(-ALPHA_, h2f((unsigned short)v[j]), 1.0f);
            }
            segprod[g8 * 64 + m_s] = pband;
            __syncthreads();
            float R = 1.0f;
#pragma unroll
            for (int gg = 1; gg < 8; ++gg)
                if (g8 + gg < 8) R *= segprod[(g8 + gg) * 64 + m_s];
            if (g8 == 0)
                chunkprod[(size_t)chunkIdx * 64 + m_s] = R * pband;
#pragma unroll
            for (int oct = 3; oct >= 0; --oct) {
                short8 v = *reinterpret_cast<const short8*>(rowp + oct * 8);
                short8 o;
#pragma unroll
                for (int j = 7; j >= 0; --j) {
                    float w = h2f((unsigned short)v[j]);
                    _Float16 we = (_Float16)(ALPHA_ * w * R);
                    o[j] = (short)__builtin_bit_cast(unsigned short, we);
                    R *= fmaf(-ALPHA_, w, 1.0f);
                }
                *reinterpret_cast<short8*>(rowp + oct * 8) = o;
            }
        }
        __syncthreads();   // w_eff + Hh visible

        // partial GEMM: pacc[m][d] += w_eff^T . H_head; wave = (mt=w&3, dh=w>>2)
        {
            const int mt = wv & 3;
            const int dh = wv >> 2;
            f32x4 pacc[2] = {};
#pragma unroll
            for (int ks = 0; ks < 8; ++ks) {
                half8 a = *reinterpret_cast<const half8*>(
                    wT + (mt * 16 + l15) * 264 + ks * 32 + q4 * 8);
#pragma unroll
                for (int dt = 0; dt < 2; ++dt) {
                    half8 bb = *reinterpret_cast<const half8*>(
                        Hh + (dh * 32 + dt * 16 + l15) * 264 + ks * 32 + q4 * 8);
                    pacc[dt] = __builtin_amdgcn_mfma_f32_16x16x32_f16(
                        a, bb, pacc[dt], 0, 0, 0);
                }
            }
#pragma unroll
            for (int dt = 0; dt < 2; ++dt)
#pragma unroll
                for (int rg = 0; rg < 4; ++rg)
                    partial[((size_t)chunkIdx * 64 + mt * 16 + q4 * 4 + rg) * 64
                            + dh * 32 + dt * 16 + l15] = pacc[dt][rg];
        }
    }
}

// ---------------------------------------------------------------------------
// Kernel 2: combine 16 chunks; grid (12, 8, 4) — mg picks 16 m-rows.
// ---------------------------------------------------------------------------
__global__ __launch_bounds__(256) void k2(const float* __restrict__ chunkprod,
                                          const float* __restrict__ partial,
                                          const float* __restrict__ s0,
                                          float* __restrict__ out) {
    const int h = blockIdx.x;
    const int b = blockIdx.y;
    const int mg = blockIdx.z;
    const int tid = threadIdx.x;
    const int m  = mg * 16 + (tid >> 4);
    const int d0 = (tid & 15) * 4;

    const size_t cpBase = (size_t)(b * NH_ + h) * CCH;
    float sfx[CCH];
    float run = 1.0f;
#pragma unroll
    for (int c = CCH - 1; c >= 0; --c) {
        sfx[c] = run;
        run *= chunkprod[(cpBase + c) * M_ + m];
    }
    const float4 v0 = *reinterpret_cast<const float4*>(
        s0 + (size_t)m * D_ + h * 64 + d0);
    float4 acc = make_float4(v0.x * run, v0.y * run, v0.z * run, v0.w * run);
#pragma unroll
    for (int c = 0; c < CCH; ++c) {
        const float sv = sfx[c];
        const float4 pp = *reinterpret_cast<const float4*>(
            partial + ((cpBase + c) * M_ + m) * 64 + d0);
        acc.x = fmaf(sv, pp.x, acc.x);
        acc.y = fmaf(sv, pp.y, acc.y);
        acc.z = fmaf(sv, pp.z, acc.z);
        acc.w = fmaf(sv, pp.w, acc.w);
    }
    *reinterpret_cast<float4*>(out + (size_t)(b * M_ + m) * D_ + h * 64 + d0) = acc;
}

// ---------------------------------------------------------------------------
extern "C" void kernel_launch(void* const* d_in, const int* in_sizes, int n_in,
                              void* d_out, int out_size, void* d_ws, size_t ws_size,
                              hipStream_t stream) {
    const float* H     = (const float*)d_in[0];
    const float* proto = (const float*)d_in[1];
    const float* W     = (const float*)d_in[2];
    const float* s0    = (const float*)d_in[3];
    float* out = (float*)d_out;

    // ws: H16 u16[25165824] (50.3 MB) | P16 u16[589824] (1.18 MB)
    //     | chunkprod f32[98304] | partial f32[6291456] (25.2 MB)   ~77 MB
    unsigned short* H16 = (unsigned short*)d_ws;
    unsigned short* P16 = (unsigned short*)((unsigned char*)d_ws + 50331648);
    float* chunkprod = (float*)((unsigned char*)d_ws + 51511296);
    float* partial   = (float*)((unsigned char*)d_ws + 51904512);

    kH16<<<dim3(6144), 256, 0, stream>>>(H, H16);
    kP<<<dim3(6, NH_), 256, 0, stream>>>(proto, W, P16);
    k1<<<dim3(768), 512, LDS_BYTES, stream>>>(H16, P16, chunkprod, partial);
    k2<<<dim3(NH_, B_, 4), 256, 0, stream>>>(chunkprod, partial, s0, out);
}